// Round 2
// baseline (268.984 us; speedup 1.0000x reference)
//
#include <hip/hip_runtime.h>
#include <stdint.h>

// ClusteringLayer: q = rownorm(1/(1 + ||x||^2 + ||c||^2 - 2 x@c^T))
// N=65536, D=512, K=512.
// v3: barrier-free K-loop. The whole 64x512 A-tile is staged to LDS as bf16
// ONCE (single barrier), then the full K=512 MFMA loop runs with no
// synchronization at all: A frags from swizzled LDS, B frags direct from the
// L2-resident fragment-major image, B software-pipelined in two named
// register sets. Removes the per-chunk barrier convoy + per-chunk exposed
// HBM latency that capped v1/v2 at ~350 TF-equivalent.

#define D 512
#define K 512
#define BM 64
#define NKS (D / 32)     // 16 k-steps of 32
#define THREADS 512
#define ESTRIDE 516      // padded f32 row stride for epilogue transpose slices

typedef __attribute__((ext_vector_type(8))) short short8;   // 8 x bf16
typedef __attribute__((ext_vector_type(4))) float floatx4;  // MFMA acc

// fp32 -> bf16 round-to-nearest-even
__device__ __forceinline__ uint16_t f2bf(float f) {
  uint32_t u = __float_as_uint(f);
  u += 0x7FFFu + ((u >> 16) & 1u);
  return (uint16_t)(u >> 16);
}

__device__ __forceinline__ uint4 pack8(float4 v0, float4 v1) {
  uint4 pk;
  pk.x = (uint32_t)f2bf(v0.x) | ((uint32_t)f2bf(v0.y) << 16);
  pk.y = (uint32_t)f2bf(v0.z) | ((uint32_t)f2bf(v0.w) << 16);
  pk.z = (uint32_t)f2bf(v1.x) | ((uint32_t)f2bf(v1.y) << 16);
  pk.w = (uint32_t)f2bf(v1.z) | ((uint32_t)f2bf(v1.w) << 16);
  return pk;
}

__device__ __forceinline__ float sq8(float4 v0, float4 v1) {
  return v0.x*v0.x + v0.y*v0.y + v0.z*v0.z + v0.w*v0.w
       + v1.x*v1.x + v1.y*v1.y + v1.z*v1.z + v1.w*v1.w;
}

// ---------------------------------------------------------------------------
// Prep: centroids fp32 -> bf16 in fragment-major layout (unchanged from v2):
//   16B slot = (ks*512 + row)*4 + quad,  ks = 0..15 (k-step of 32)
// A wave's fragment read (fixed ks,ni) is one contiguous, coalesced 1KB.
// Also ||c||^2 per centroid.
// ---------------------------------------------------------------------------
__global__ __launch_bounds__(64)
void prep_kernel(const float* __restrict__ cent, float* __restrict__ csq,
                 uint16_t* __restrict__ bbf) {
  const int row  = blockIdx.x;     // 0..511
  const int lane = threadIdx.x;    // 0..63, 8 floats each
  const float4* src = (const float4*)(cent + (size_t)row * D + lane * 8);
  float4 v0 = src[0];
  float4 v1 = src[1];
  float ss = sq8(v0, v1);
  uint4 pk = pack8(v0, v1);
  const int ks = lane >> 2;        // k-step (8 floats per lane => lane/4)
  const int qd = lane & 3;         // quad within k-step
  const int slot = (ks * 512 + row) * 4 + qd;
  *(uint4*)(bbf + (size_t)slot * 8) = pk;
  #pragma unroll
  for (int m = 1; m < 64; m <<= 1) ss += __shfl_xor(ss, m);
  if (lane == 0) csq[row] = ss;
}

// ---------------------------------------------------------------------------
// Main fused kernel. Block = 64 rows x all 512 centroids, 8 waves;
// wave w owns cols [64w, 64w+64): 4x4 grid of 16x16x32 bf16 MFMA.
// ---------------------------------------------------------------------------
__global__ __launch_bounds__(THREADS, 4)
void cluster_main(const float* __restrict__ x, const uint16_t* __restrict__ bbf,
                  const float* __restrict__ csq, float* __restrict__ out) {
  // smem: K-loop uses it as the full A tile [64 rows][64 groups of 8 bf16],
  // XOR-swizzled (64 KB); epilogue reuses it as a [16][516] f32 transpose
  // buffer (33 KB). 64.5 KB total LDS -> 2 blocks/CU.
  __shared__ __align__(16) char smem[BM * D * 2];
  __shared__ float lxsq[BM];
  __shared__ float lrow[BM];
  uint16_t* const lA = (uint16_t*)smem;
  float* const ebuf  = (float*)smem;

  const int tid  = threadIdx.x;
  const int wave = tid >> 6;
  const int lane = tid & 63;
  const int p    = lane & 15;     // MFMA row/col-within-16
  const int quad = lane >> 4;     // MFMA quad
  const int row0 = blockIdx.x * BM;

  if (tid < BM) lrow[tid] = 0.f;

  // ---- stage the FULL A tile (64x512 fp32 -> bf16, swizzled), once ----
  // thread -> (row ar, 8-col phase ag); covers groups gi ≡ ag (mod 8).
  const int ar = tid >> 3;        // 0..63
  const int ag = tid & 7;
  const float* xrow = x + (size_t)(row0 + ar) * D + ag * 8;
  float xacc = 0.f;
  #pragma unroll
  for (int h = 0; h < 2; ++h) {
    float4 v[8];
    #pragma unroll
    for (int j = 0; j < 4; ++j) {
      v[2*j]   = *(const float4*)(xrow + (h*4 + j) * 64);
      v[2*j+1] = *(const float4*)(xrow + (h*4 + j) * 64 + 4);
    }
    #pragma unroll
    for (int j = 0; j < 4; ++j) {
      xacc += sq8(v[2*j], v[2*j+1]);
      const int gi = (h*4 + j) * 8 + ag;                 // group 0..63
      *(uint4*)(lA + (size_t)ar * 512 + ((gi ^ (ar & 7)) * 8)) =
          pack8(v[2*j], v[2*j+1]);
    }
  }
  // ||x||^2: 8 contributing lanes per row are consecutive (same wave)
  xacc += __shfl_xor(xacc, 1);
  xacc += __shfl_xor(xacc, 2);
  xacc += __shfl_xor(xacc, 4);
  if (ag == 0) lxsq[ar] = xacc;

  floatx4 acc[4][4];
  #pragma unroll
  for (int mi = 0; mi < 4; ++mi)
    #pragma unroll
    for (int ni = 0; ni < 4; ++ni)
      acc[mi][ni] = (floatx4){0.f, 0.f, 0.f, 0.f};

  __syncthreads();   // the ONLY main-loop barrier

  // ---- barrier-free K loop: 16 k-steps, B software-pipelined (bE/bO) ----
  // per-lane B base (u16 units) into the fragment-major image
  const uint16_t* const bl = bbf + ((wave * 64 + p) * 32 + quad * 8);

  short8 bE[4], bO[4];
  #pragma unroll
  for (int ni = 0; ni < 4; ++ni)
    bE[ni] = *(const short8*)(bl + ni * 512);

  #pragma unroll
  for (int s = 0; s < 8; ++s) {
    const int ks0 = 2 * s, ks1 = 2 * s + 1;

    // issue odd-step B while even-step MFMAs run
    #pragma unroll
    for (int ni = 0; ni < 4; ++ni)
      bO[ni] = *(const short8*)(bl + ks1 * 16384 + ni * 512);

    #pragma unroll
    for (int mi = 0; mi < 4; ++mi) {
      const int r = mi * 16 + p;
      short8 af = *(const short8*)(
          lA + (size_t)r * 512 + ((((ks0 * 4 + quad) ^ (r & 7))) * 8));
      #pragma unroll
      for (int ni = 0; ni < 4; ++ni)
        acc[mi][ni] = __builtin_amdgcn_mfma_f32_16x16x32_bf16(
            af, bE[ni], acc[mi][ni], 0, 0, 0);
    }

    // issue next even-step B
    if (s < 7) {
      #pragma unroll
      for (int ni = 0; ni < 4; ++ni)
        bE[ni] = *(const short8*)(bl + (ks0 + 2) * 16384 + ni * 512);
    }

    #pragma unroll
    for (int mi = 0; mi < 4; ++mi) {
      const int r = mi * 16 + p;
      short8 af = *(const short8*)(
          lA + (size_t)r * 512 + ((((ks1 * 4 + quad) ^ (r & 7))) * 8));
      #pragma unroll
      for (int ni = 0; ni < 4; ++ni)
        acc[mi][ni] = __builtin_amdgcn_mfma_f32_16x16x32_bf16(
            af, bO[ni], acc[mi][ni], 0, 0, 0);
    }
  }

  // ---- epilogue: q = rcp(1 + xsq + csq - 2*dot); fused row-normalize ----
  float xs[4][4];
  #pragma unroll
  for (int mi = 0; mi < 4; ++mi)
    #pragma unroll
    for (int rr = 0; rr < 4; ++rr)
      xs[mi][rr] = lxsq[mi * 16 + quad * 4 + rr];
  float cs[4];
  #pragma unroll
  for (int ni = 0; ni < 4; ++ni)
    cs[ni] = csq[wave * 64 + ni * 16 + p];   // tiny, L2-hot

  float rp[4][4];
  #pragma unroll
  for (int mi = 0; mi < 4; ++mi)
    #pragma unroll
    for (int rr = 0; rr < 4; ++rr)
      rp[mi][rr] = 0.f;

  #pragma unroll
  for (int mi = 0; mi < 4; ++mi)
    #pragma unroll
    for (int ni = 0; ni < 4; ++ni)
      #pragma unroll
      for (int rr = 0; rr < 4; ++rr) {
        const float d = 1.0f + xs[mi][rr] + cs[ni] - 2.0f * acc[mi][ni][rr];
        const float q = __builtin_amdgcn_rcpf(d);  // d ~ 1000, 1ulp is plenty
        acc[mi][ni][rr] = q;
        rp[mi][rr] += q;
      }

  #pragma unroll
  for (int mi = 0; mi < 4; ++mi)
    #pragma unroll
    for (int rr = 0; rr < 4; ++rr) {
      float v = rp[mi][rr];
      v += __shfl_xor(v, 1);
      v += __shfl_xor(v, 2);
      v += __shfl_xor(v, 4);
      v += __shfl_xor(v, 8);
      if (p == 0) atomicAdd(&lrow[mi * 16 + quad * 4 + rr], v);
    }
  __syncthreads();   // also fences last lA reads before ebuf overwrite

  float inv[4][4];
  #pragma unroll
  for (int mi = 0; mi < 4; ++mi)
    #pragma unroll
    for (int rr = 0; rr < 4; ++rr)
      inv[mi][rr] = __builtin_amdgcn_rcpf(lrow[mi * 16 + quad * 4 + rr]);

  // Transposed store through LDS (reusing the dead A tile): 4 slices of
  // 16 rows (slice s == fragment row-block mi=s); padded stride keeps LDS
  // conflict-free; stores are contiguous 1KB float4 runs per wave.
  #pragma unroll
  for (int s = 0; s < 4; ++s) {
    if (s) __syncthreads();        // prior slice's reads complete
    #pragma unroll
    for (int ni = 0; ni < 4; ++ni)
      #pragma unroll
      for (int rr = 0; rr < 4; ++rr)
        ebuf[(quad * 4 + rr) * ESTRIDE + wave * 64 + ni * 16 + p] =
            acc[s][ni][rr] * inv[s][rr];
    __syncthreads();
    #pragma unroll
    for (int j = 0; j < 4; ++j) {
      const int idx = j * 512 + tid;       // 0..2047
      const int r  = idx >> 7;             // 0..15
      const int c4 = idx & 127;            // float4 column
      const float4 v = *(const float4*)&ebuf[r * ESTRIDE + c4 * 4];
      *(float4*)(out + (size_t)(row0 + s * 16 + r) * K + c4 * 4) = v;
    }
  }
}

extern "C" void kernel_launch(void* const* d_in, const int* in_sizes, int n_in,
                              void* d_out, int out_size, void* d_ws, size_t ws_size,
                              hipStream_t stream) {
  const float* x    = (const float*)d_in[0];
  const float* cent = (const float*)d_in[1];
  float* out = (float*)d_out;

  // ws layout: csq[512] floats (2KB) | bbf bf16 image (512KB). Needs 526KB.
  float*    csq = (float*)d_ws;
  uint16_t* bbf = (uint16_t*)((char*)d_ws + 2048);

  const int N = in_sizes[0] / D;      // 65536
  prep_kernel<<<K, 64, 0, stream>>>(cent, csq, bbf);
  cluster_main<<<N / BM, THREADS, 0, stream>>>(x, bbf, csq, out);
}